// Round 1
// baseline (177.478 us; speedup 1.0000x reference)
//
#include <hip/hip_runtime.h>

// Problem constants (from reference): x [B=128, C=3, L=256, L=256] fp32,
// X/Y/W/H [N=4, B=128] int32 box bounds. Output: x with pixels inside any
// box zeroed (mask broadcast over C).
//
// Memory-bound: ~201 MB traffic. One thread per float4; each wave covers one
// full image row (64 float4 = 256 cols) so row-predicates are wave-uniform.

constexpr int BB = 128;
constexpr int CC = 3;
constexpr int LL = 256;
constexpr int NN = 4;

__global__ __launch_bounds__(256) void mask_square_kernel(
    const float4* __restrict__ x,
    const int* __restrict__ Xb,
    const int* __restrict__ Yb,
    const int* __restrict__ Wb,
    const int* __restrict__ Hb,
    float4* __restrict__ out)
{
    const int i4   = blockIdx.x * 256 + threadIdx.x;   // float4 index
    const int col0 = (i4 & 63) << 2;                   // first col of this group of 4
    const int row  = (i4 >> 6) & (LL - 1);
    const int bc   = i4 >> 14;                         // b*C + c  (64*256 float4 per plane)
    const int b    = bc / CC;                          // block-uniform

    float4 v = x[i4];

    int m0 = 0, m1 = 0, m2 = 0, m3 = 0;
#pragma unroll
    for (int n = 0; n < NN; ++n) {
        const int Xn = Xb[n * BB + b];
        const int Yn = Yb[n * BB + b];
        const int Wn = Wb[n * BB + b];
        const int Hn = Hb[n * BB + b];
        const int rin = (row >= Yn) & (row <= Yn + Hn);   // wave-uniform
        const int lo = Xn, hi = Xn + Wn;
        m0 |= rin & (col0     >= lo) & (col0     <= hi);
        m1 |= rin & (col0 + 1 >= lo) & (col0 + 1 <= hi);
        m2 |= rin & (col0 + 2 >= lo) & (col0 + 2 <= hi);
        m3 |= rin & (col0 + 3 >= lo) & (col0 + 3 <= hi);
    }
    if (m0) v.x = 0.0f;
    if (m1) v.y = 0.0f;
    if (m2) v.z = 0.0f;
    if (m3) v.w = 0.0f;

    out[i4] = v;
}

extern "C" void kernel_launch(void* const* d_in, const int* in_sizes, int n_in,
                              void* d_out, int out_size, void* d_ws, size_t ws_size,
                              hipStream_t stream) {
    const float4* x  = (const float4*)d_in[0];
    const int*    Xb = (const int*)d_in[1];
    const int*    Yb = (const int*)d_in[2];
    const int*    Wb = (const int*)d_in[3];
    const int*    Hb = (const int*)d_in[4];
    float4*       o  = (float4*)d_out;

    const int total4 = BB * CC * LL * LL / 4;   // 6,291,456
    const int blocks = total4 / 256;            // 24,576
    mask_square_kernel<<<blocks, 256, 0, stream>>>(x, Xb, Yb, Wb, Hb, o);
}